// Round 3
// baseline (364.771 us; speedup 1.0000x reference)
//
#include <hip/hip_runtime.h>
#include <hip/hip_bf16.h>

// KGAT-style 2-hop relational graph attention on MI355X — round 10
// (= round 9 resubmitted: bench infra failed twice, no kernel verdict).
//
// vs round 8 (300.7 us; fill_bucket 65 us now the largest dispatch —
// it re-reads the 4.8 MB head stream 16x (color passes) + masked tail/type,
// ~160 MB moved for a 14.4 MB->19.2 MB job):
//  1. Two-phase partition replaces colored fill. route: single pass over
//     edges, LDS per-color histogram, one global atomicAdd per (block,color),
//     scatter 8 B records (tail|type<<18, head) into 16 per-color queues.
//     fill2: per color, stream the queue and do the identical band-local
//     cursor-atomic + bucket scatter (L2-resident band) as before.
//     Traffic ~160 MB -> ~55 MB. Queues alias h1b (dead until hop1).
//  2. Everything else (degree-grouped hop schedule, bf16 tables) unchanged.
//
// dtypes: all float32 (reference), indices int32 (harness int64->int32).

#define N_ENT  200000
#define N_EDGE 1200000
#define N_REL  32
#define DIM    64
#define LEAKY  0.2f
#define CAP    32                                      // bucket slots per head
#define NCOLOR 16
#define BAND (N_ENT / NCOLOR)                          // 12500 heads per color
#define NBIN   (CAP + 1)                               // degree bins 0..32
#define QCAP   80000                                   // records per color queue
#define BPC    40                                      // fill2 blocks per color

template <int CTRL>
__device__ __forceinline__ float dpp_add(float x) {
  int t = __builtin_amdgcn_update_dpp(0, __float_as_int(x), CTRL, 0xF, 0xF, true);
  return x + __int_as_float(t);
}
// 16-lane (DPP row) allreduce sum; result valid in all 16 lanes of the row.
__device__ __forceinline__ float red16(float x) {
  x = dpp_add<0xB1>(x);    // quad_perm [1,0,3,2]  (xor 1)
  x = dpp_add<0x4E>(x);    // quad_perm [2,3,0,1]  (xor 2)
  x = dpp_add<0x124>(x);   // row_ror:4
  x = dpp_add<0x128>(x);   // row_ror:8
  return x;
}

// 4 bf16 (as 2 uints, low/high packed) -> float4
__device__ __forceinline__ float4 unpack4(uint2 u) {
  float4 t;
  t.x = __uint_as_float(u.x << 16);
  t.y = __uint_as_float(u.x & 0xFFFF0000u);
  t.z = __uint_as_float(u.y << 16);
  t.w = __uint_as_float(u.y & 0xFFFF0000u);
  return t;
}
// two f32 -> packed bf16 pair (round-to-nearest-even)
__device__ __forceinline__ unsigned pk(float a, float b) {
  unsigned ua = __float_as_uint(a);
  ua += 0x7FFFu + ((ua >> 16) & 1u);
  unsigned ub = __float_as_uint(b);
  ub += 0x7FFFu + ((ub >> 16) & 1u);
  return (ua >> 16) | (ub & 0xFFFF0000u);
}

// prep: build Q (Q[r*128+k] = W[k,:] . R[r,:]) + convert ent0 -> bf16 table
//       + zero cursor / degree hist / color-queue counts
__global__ void prep(const float* __restrict__ W, const float* __restrict__ R,
                     float* __restrict__ Q,
                     const float4* __restrict__ ent04,
                     uint2* __restrict__ ent0b,
                     int* __restrict__ cursor,
                     int* __restrict__ hist,
                     int* __restrict__ qcnt) {
  int i = blockIdx.x * blockDim.x + threadIdx.x;
  if (i < N_REL * 2 * DIM) {
    int r = i >> 7;
    int k = i & 127;
    float acc = 0.f;
#pragma unroll 8
    for (int j = 0; j < DIM; ++j)
      acc += W[k * DIM + j] * R[r * DIM + j];
    Q[i] = acc;
  }
  if (i < N_ENT) cursor[i] = 0;
  if (i < NBIN) hist[i] = 0;
  if (i < NCOLOR) qcnt[i] = 0;
  if (i < N_ENT * DIM / 4) {
    float4 v = ent04[i];
    ent0b[i] = make_uint2(pk(v.x, v.y), pk(v.z, v.w));
  }
}

// route: single pass over edges; partition into 16 per-color queues.
// Record = (tail | type<<18, head). Block-aggregated: LDS rank + one global
// atomicAdd per (block, color) -> per-color ~512 B contiguous chunks.
__global__ void route(const int4* __restrict__ head4,
                      const int4* __restrict__ tail4,
                      const int4* __restrict__ type4,
                      int* __restrict__ qcnt,
                      uint2* __restrict__ qdata) {
  __shared__ int lcnt[NCOLOR];
  __shared__ int lbase[NCOLOR];
  if (threadIdx.x < NCOLOR) lcnt[threadIdx.x] = 0;
  __syncthreads();
  int i = blockIdx.x * blockDim.x + threadIdx.x;
  bool valid = (i < N_EDGE / 4);
  int4 h = make_int4(0, 0, 0, 0), t = h, r = h;
  int c0 = 0, c1 = 0, c2 = 0, c3 = 0;
  int k0 = 0, k1 = 0, k2 = 0, k3 = 0;
  if (valid) {
    h = head4[i];
    t = tail4[i];
    r = type4[i];
    c0 = h.x / BAND; c1 = h.y / BAND; c2 = h.z / BAND; c3 = h.w / BAND;
    k0 = atomicAdd(&lcnt[c0], 1);
    k1 = atomicAdd(&lcnt[c1], 1);
    k2 = atomicAdd(&lcnt[c2], 1);
    k3 = atomicAdd(&lcnt[c3], 1);
  }
  __syncthreads();
  if (threadIdx.x < NCOLOR)
    lbase[threadIdx.x] = atomicAdd(&qcnt[threadIdx.x], lcnt[threadIdx.x]);
  __syncthreads();
  if (valid) {
    int p;
    p = lbase[c0] + k0;
    if (p < QCAP) qdata[c0 * QCAP + p] = make_uint2((unsigned)t.x | ((unsigned)r.x << 18), (unsigned)h.x);
    p = lbase[c1] + k1;
    if (p < QCAP) qdata[c1 * QCAP + p] = make_uint2((unsigned)t.y | ((unsigned)r.y << 18), (unsigned)h.y);
    p = lbase[c2] + k2;
    if (p < QCAP) qdata[c2 * QCAP + p] = make_uint2((unsigned)t.z | ((unsigned)r.z << 18), (unsigned)h.z);
    p = lbase[c3] + k3;
    if (p < QCAP) qdata[c3 * QCAP + p] = make_uint2((unsigned)t.w | ((unsigned)r.w << 18), (unsigned)h.w);
  }
}

// fill2: per color, stream the queue; band-local cursor atomic + bucket write
// (bucket[h*CAP + slot] = tail | (type << 18)) — same scatter pattern as the
// old colored fill, minus the 16x head-stream re-read.
__global__ void fill2(const int* __restrict__ qcnt,
                      const uint2* __restrict__ qdata,
                      int* __restrict__ cursor,
                      unsigned* __restrict__ bucket) {
  int c = blockIdx.x / BPC;
  int slice = blockIdx.x - c * BPC;
  int n = min(qcnt[c], QCAP);
  const uint2* q = qdata + (size_t)c * QCAP;
  for (int k = slice * blockDim.x + threadIdx.x; k < n; k += BPC * blockDim.x) {
    uint2 rec = q[k];
    int hh = (int)rec.y;
    int p = atomicAdd(&cursor[hh], 1);
    if (p < CAP) bucket[hh * CAP + p] = rec.x;
  }
}

// ---- counting sort of heads by clamped degree (33 bins) ----
__global__ void hist_deg(const int* __restrict__ cnt, int* __restrict__ hist) {
  __shared__ int lh[NBIN];
  if (threadIdx.x < NBIN) lh[threadIdx.x] = 0;
  __syncthreads();
  int i = blockIdx.x * blockDim.x + threadIdx.x;
  if (i < N_ENT) atomicAdd(&lh[min(cnt[i], CAP)], 1);
  __syncthreads();
  if (threadIdx.x < NBIN) atomicAdd(&hist[threadIdx.x], lh[threadIdx.x]);
}

__global__ void scan_deg(const int* __restrict__ hist, int* __restrict__ binCur) {
  if (threadIdx.x == 0) {
    int s = 0;
    for (int b = 0; b < NBIN; ++b) { binCur[b] = s; s += hist[b]; }
  }
}

// order[pos] = n | (len << 18); heads grouped by degree -> equal trip counts
// for the 4 groups of a wave. Block-aggregated scatter: LDS atomics give the
// in-block rank, one global atomicAdd per (block, bin) claims the base.
__global__ void scatter_deg(const int* __restrict__ cnt,
                            int* __restrict__ binCur,
                            unsigned* __restrict__ order) {
  __shared__ int lh[NBIN];
  __shared__ int lbase[NBIN];
  if (threadIdx.x < NBIN) lh[threadIdx.x] = 0;
  __syncthreads();
  int i = blockIdx.x * blockDim.x + threadIdx.x;
  int d = 0, rank = 0;
  bool valid = (i < N_ENT);
  if (valid) {
    d = min(cnt[i], CAP);
    rank = atomicAdd(&lh[d], 1);
  }
  __syncthreads();
  if (threadIdx.x < NBIN)
    lbase[threadIdx.x] = atomicAdd(&binCur[threadIdx.x], lh[threadIdx.x]);
  __syncthreads();
  if (valid)
    order[lbase[d] + rank] = (unsigned)i | ((unsigned)d << 18);
}

// persistent hop kernel: wave = 4 groups x 16 lanes, 4 heads/wave, heads taken
// from the degree-sorted order[] (len packed in bits 18..23 -> no cnt load).
// Gathers are bf16 rows (128 B = 1 line). Softmax un-maxed (logits << 88).
// HOP==1: heads = ent0 (f32), gather = ent0b, out = h1b (bf16)
// HOP==2: heads = h1b, gather = h1b, out = 0.25*ent0 + 0.5*eh + h2 (f32)
template <int HOP>
__global__ __launch_bounds__(256, 8) void hop_kernel(
    const float* __restrict__ ent0,
    const ushort* __restrict__ entb,     // bf16 gather table
    const float4* __restrict__ Qg,
    const unsigned* __restrict__ order,
    const unsigned* __restrict__ bucket,
    uint2* __restrict__ outb,            // HOP1
    float* __restrict__ outf) {          // HOP2
  __shared__ float4 sQ[N_REL * 32];   // [r][half(2)][sub(16)]
  for (int i = threadIdx.x; i < N_REL * 32; i += blockDim.x) sQ[i] = Qg[i];
  __syncthreads();
  const int lane = threadIdx.x & 63;
  const int sub = lane & 15;
  const int grp = lane >> 4;
  const int wave = (blockIdx.x * blockDim.x + threadIdx.x) >> 6;
  const int nWaves = (gridDim.x * blockDim.x) >> 6;
  const uint2* gtab = (const uint2*)entb;
  for (int n4 = wave * 4; n4 < N_ENT; n4 += nWaves * 4) {
    unsigned oe = order[n4 + grp];    // N_ENT % 4 == 0 -> always < N_ENT
    int n = (int)(oe & 0x3FFFFu);
    int len = (int)(oe >> 18);
    float4 eh;
    if (HOP == 1)
      eh = ((const float4*)(ent0 + (size_t)n * DIM))[sub];
    else
      eh = unpack4(gtab[(size_t)n * 16 + sub]);
    int b = n * CAP;
    float l = 0.f;
    float4 acc = make_float4(0.f, 0.f, 0.f, 0.f);
    // depth-2 software pipeline over the segment (predicated per group)
    unsigned p0 = 0u, p1 = 0u;
    uint2 t0 = make_uint2(0u, 0u), t1 = t0;
    if (0 < len) { p0 = bucket[b];     t0 = gtab[(size_t)(p0 & 0x3FFFFu) * 16 + sub]; }
    if (1 < len) { p1 = bucket[b + 1]; t1 = gtab[(size_t)(p1 & 0x3FFFFu) * 16 + sub]; }
    for (int i = 0; __any(i < len); ++i) {
      unsigned p2 = 0u;
      uint2 t2 = make_uint2(0u, 0u);
      if (i + 2 < len) { p2 = bucket[b + i + 2];
                         t2 = gtab[(size_t)(p2 & 0x3FFFFu) * 16 + sub]; }
      if (i < len) {
        int r = (int)(p0 >> 18);
        float4 qh = sQ[r * 32 + sub];
        float4 qt = sQ[r * 32 + 16 + sub];
        float4 et = unpack4(t0);
        float d = eh.x * qh.x + eh.y * qh.y + eh.z * qh.z + eh.w * qh.w
                + et.x * qt.x + et.y * qt.y + et.z * qt.z + et.w * qt.w;
        d = red16(d);
        float v = d > 0.f ? d : LEAKY * d;
        float ex = __expf(v);
        l += ex;
        acc.x = fmaf(ex, et.x, acc.x);
        acc.y = fmaf(ex, et.y, acc.y);
        acc.z = fmaf(ex, et.z, acc.z);
        acc.w = fmaf(ex, et.w, acc.w);
      }
      p0 = p1; t0 = t1; p1 = p2; t1 = t2;
    }
    float inv = (l > 0.f) ? 1.f / l : 0.f;
    float4 v;
    v.x = fmaf(acc.x, inv, eh.x);
    v.y = fmaf(acc.y, inv, eh.y);
    v.z = fmaf(acc.z, inv, eh.z);
    v.w = fmaf(acc.w, inv, eh.w);
    float s = v.x * v.x + v.y * v.y + v.z * v.z + v.w * v.w;
    s = red16(s);
    float rn = 1.f / fmaxf(sqrtf(s), 1e-12f);
    if (HOP == 1) {
      outb[(size_t)n * 16 + sub] = make_uint2(pk(v.x * rn, v.y * rn),
                                              pk(v.z * rn, v.w * rn));
    } else {
      float4 e0 = ((const float4*)(ent0 + (size_t)n * DIM))[sub];
      float4 o;
      o.x = fmaf(0.25f, e0.x, fmaf(0.5f, eh.x, v.x * rn));
      o.y = fmaf(0.25f, e0.y, fmaf(0.5f, eh.y, v.y * rn));
      o.z = fmaf(0.25f, e0.z, fmaf(0.5f, eh.z, v.z * rn));
      o.w = fmaf(0.25f, e0.w, fmaf(0.5f, eh.w, v.w * rn));
      ((float4*)(outf + (size_t)n * DIM))[sub] = o;
    }
  }
}

extern "C" void kernel_launch(void* const* d_in, const int* in_sizes, int n_in,
                              void* d_out, int out_size, void* d_ws, size_t ws_size,
                              hipStream_t stream) {
  const float* ent0 = (const float*)d_in[0];
  const float* rel  = (const float*)d_in[1];
  const float* W    = (const float*)d_in[2];
  const int* edge_index = (const int*)d_in[3];
  const int* etype      = (const int*)d_in[4];
  const int* head = edge_index;            // edge_index[0, :]
  const int* tail = edge_index + N_EDGE;   // edge_index[1, :]
  float* out = (float*)d_out;

  // workspace (~78.4 MB): Q | cursor | bucket | ent0b | h1b | order | hist |
  // binCur | qcnt  (128 B-aligned). Color queues ALIAS h1b (dead until hop1):
  // 16 x 80000 x 8 B = 10.24 MB <= 25.6 MB.
  char* ws = (char*)d_ws;
  float*    Q      = (float*)ws;                              // 16384 B
  int*      cursor = (int*)(ws + 16384);                      // 800000 B
  unsigned* bucket = (unsigned*)(ws + 816384);                // 25.6 MB
  ushort*   ent0b  = (ushort*)(ws + 816384 + 25600000);       // 25.6 MB
  ushort*   h1b    = (ushort*)(ws + 816384 + 51200000);       // 25.6 MB
  unsigned* order  = (unsigned*)(ws + 816384 + 76800000);     // 800000 B
  int*      hist   = (int*)(ws + 816384 + 77600000);          // 132 B (pad 128)
  int*      binCur = (int*)(ws + 816384 + 77600128);          // 132 B (pad 128)
  int*      qcnt   = (int*)(ws + 816384 + 77600256);          // 64 B
  uint2*    qdata  = (uint2*)h1b;                             // aliased

  // ---- preamble: prep (Q + bf16 table + zero counters) ----
  prep<<<(N_ENT * DIM / 4 + 255) / 256, 256, 0, stream>>>(
      W, rel, Q, (const float4*)ent0, (uint2*)ent0b, cursor, hist, qcnt);

  // ---- two-phase bucket build: route (1 pass) + fill2 (band-local) ----
  route<<<(N_EDGE / 4 + 255) / 256, 256, 0, stream>>>(
      (const int4*)head, (const int4*)tail, (const int4*)etype, qcnt, qdata);
  fill2<<<NCOLOR * BPC, 256, 0, stream>>>(qcnt, qdata, cursor, bucket);

  // ---- degree-grouped schedule: counting sort of heads (33 bins) ----
  hist_deg<<<(N_ENT + 255) / 256, 256, 0, stream>>>(cursor, hist);
  scan_deg<<<1, 64, 0, stream>>>(hist, binCur);
  scatter_deg<<<(N_ENT + 255) / 256, 256, 0, stream>>>(cursor, binCur, order);

  // ---- hops: one persistent kernel each ----
  hop_kernel<1><<<2048, 256, 0, stream>>>(ent0, ent0b, (const float4*)Q,
                                          order, bucket, (uint2*)h1b, nullptr);
  hop_kernel<2><<<2048, 256, 0, stream>>>(ent0, h1b, (const float4*)Q,
                                          order, bucket, nullptr, out);
}

// Round 4
// 351.622 us; speedup vs baseline: 1.0374x; 1.0374x over previous
//
#include <hip/hip_runtime.h>
#include <hip/hip_bf16.h>

// KGAT-style 2-hop relational graph attention on MI355X — round 11.
//
// vs round 10 (364.8 us; fill2 111 us: VALUBusy 0.27%, HBM 8.7%, occ 25% —
// latency-starved: 640 blocks ran ~7-deep dependent {load,atomic,store}
// chains, and all 16 colors were resident at once so the 25.6 MB bucket
// write-set thrashed L2 (WRITE stayed 72 MB)):
//  1. fill2 grid 16x40 -> 16x1250 blocks (<=1 record/thread). Restores the
//     two properties the old 65-us colored fill had: ~5M threads of TLP to
//     hide atomic latency, and dispatch-order color phasing (~1.6 colors
//     live at a time -> band bucket region L2-resident).
//  2. route (single-pass edge partition into 16 color queues) unchanged —
//     it killed the 16x head re-read (fill-phase FETCH 70 MB -> 5 MB).
//  3. Hops / degree-grouped schedule / bf16 tables unchanged.
//
// dtypes: all float32 (reference), indices int32 (harness int64->int32).

#define N_ENT  200000
#define N_EDGE 1200000
#define N_REL  32
#define DIM    64
#define LEAKY  0.2f
#define CAP    32                                      // bucket slots per head
#define NCOLOR 16
#define BAND (N_ENT / NCOLOR)                          // 12500 heads per color
#define NBIN   (CAP + 1)                               // degree bins 0..32
#define QCAP   80000                                   // records per color queue
#define BPC    1250                                    // fill2 blocks per color

template <int CTRL>
__device__ __forceinline__ float dpp_add(float x) {
  int t = __builtin_amdgcn_update_dpp(0, __float_as_int(x), CTRL, 0xF, 0xF, true);
  return x + __int_as_float(t);
}
// 16-lane (DPP row) allreduce sum; result valid in all 16 lanes of the row.
__device__ __forceinline__ float red16(float x) {
  x = dpp_add<0xB1>(x);    // quad_perm [1,0,3,2]  (xor 1)
  x = dpp_add<0x4E>(x);    // quad_perm [2,3,0,1]  (xor 2)
  x = dpp_add<0x124>(x);   // row_ror:4
  x = dpp_add<0x128>(x);   // row_ror:8
  return x;
}

// 4 bf16 (as 2 uints, low/high packed) -> float4
__device__ __forceinline__ float4 unpack4(uint2 u) {
  float4 t;
  t.x = __uint_as_float(u.x << 16);
  t.y = __uint_as_float(u.x & 0xFFFF0000u);
  t.z = __uint_as_float(u.y << 16);
  t.w = __uint_as_float(u.y & 0xFFFF0000u);
  return t;
}
// two f32 -> packed bf16 pair (round-to-nearest-even)
__device__ __forceinline__ unsigned pk(float a, float b) {
  unsigned ua = __float_as_uint(a);
  ua += 0x7FFFu + ((ua >> 16) & 1u);
  unsigned ub = __float_as_uint(b);
  ub += 0x7FFFu + ((ub >> 16) & 1u);
  return (ua >> 16) | (ub & 0xFFFF0000u);
}

// prep: build Q (Q[r*128+k] = W[k,:] . R[r,:]) + convert ent0 -> bf16 table
//       + zero cursor / degree hist / color-queue counts
__global__ void prep(const float* __restrict__ W, const float* __restrict__ R,
                     float* __restrict__ Q,
                     const float4* __restrict__ ent04,
                     uint2* __restrict__ ent0b,
                     int* __restrict__ cursor,
                     int* __restrict__ hist,
                     int* __restrict__ qcnt) {
  int i = blockIdx.x * blockDim.x + threadIdx.x;
  if (i < N_REL * 2 * DIM) {
    int r = i >> 7;
    int k = i & 127;
    float acc = 0.f;
#pragma unroll 8
    for (int j = 0; j < DIM; ++j)
      acc += W[k * DIM + j] * R[r * DIM + j];
    Q[i] = acc;
  }
  if (i < N_ENT) cursor[i] = 0;
  if (i < NBIN) hist[i] = 0;
  if (i < NCOLOR) qcnt[i] = 0;
  if (i < N_ENT * DIM / 4) {
    float4 v = ent04[i];
    ent0b[i] = make_uint2(pk(v.x, v.y), pk(v.z, v.w));
  }
}

// route: single pass over edges; partition into 16 per-color queues.
// Record = (tail | type<<18, head). Block-aggregated: LDS rank + one global
// atomicAdd per (block, color) -> per-color ~512 B contiguous chunks.
__global__ void route(const int4* __restrict__ head4,
                      const int4* __restrict__ tail4,
                      const int4* __restrict__ type4,
                      int* __restrict__ qcnt,
                      uint2* __restrict__ qdata) {
  __shared__ int lcnt[NCOLOR];
  __shared__ int lbase[NCOLOR];
  if (threadIdx.x < NCOLOR) lcnt[threadIdx.x] = 0;
  __syncthreads();
  int i = blockIdx.x * blockDim.x + threadIdx.x;
  bool valid = (i < N_EDGE / 4);
  int4 h = make_int4(0, 0, 0, 0), t = h, r = h;
  int c0 = 0, c1 = 0, c2 = 0, c3 = 0;
  int k0 = 0, k1 = 0, k2 = 0, k3 = 0;
  if (valid) {
    h = head4[i];
    t = tail4[i];
    r = type4[i];
    c0 = h.x / BAND; c1 = h.y / BAND; c2 = h.z / BAND; c3 = h.w / BAND;
    k0 = atomicAdd(&lcnt[c0], 1);
    k1 = atomicAdd(&lcnt[c1], 1);
    k2 = atomicAdd(&lcnt[c2], 1);
    k3 = atomicAdd(&lcnt[c3], 1);
  }
  __syncthreads();
  if (threadIdx.x < NCOLOR)
    lbase[threadIdx.x] = atomicAdd(&qcnt[threadIdx.x], lcnt[threadIdx.x]);
  __syncthreads();
  if (valid) {
    int p;
    p = lbase[c0] + k0;
    if (p < QCAP) qdata[c0 * QCAP + p] = make_uint2((unsigned)t.x | ((unsigned)r.x << 18), (unsigned)h.x);
    p = lbase[c1] + k1;
    if (p < QCAP) qdata[c1 * QCAP + p] = make_uint2((unsigned)t.y | ((unsigned)r.y << 18), (unsigned)h.y);
    p = lbase[c2] + k2;
    if (p < QCAP) qdata[c2 * QCAP + p] = make_uint2((unsigned)t.z | ((unsigned)r.z << 18), (unsigned)h.z);
    p = lbase[c3] + k3;
    if (p < QCAP) qdata[c3 * QCAP + p] = make_uint2((unsigned)t.w | ((unsigned)r.w << 18), (unsigned)h.w);
  }
}

// fill2: per color, stream the queue; band-local cursor atomic + bucket write
// (bucket[h*CAP + slot] = tail | (type << 18)). BPC=1250 -> <=1 record per
// thread, dispatch-order color phasing keeps the live bucket write-set
// ~1.6-3 MB (L2-resident), ~5M threads hide atomic latency.
__global__ void fill2(const int* __restrict__ qcnt,
                      const uint2* __restrict__ qdata,
                      int* __restrict__ cursor,
                      unsigned* __restrict__ bucket) {
  int c = blockIdx.x / BPC;
  int slice = blockIdx.x - c * BPC;
  int n = min(qcnt[c], QCAP);
  const uint2* q = qdata + (size_t)c * QCAP;
  for (int k = slice * blockDim.x + threadIdx.x; k < n; k += BPC * blockDim.x) {
    uint2 rec = q[k];
    int hh = (int)rec.y;
    int p = atomicAdd(&cursor[hh], 1);
    if (p < CAP) bucket[hh * CAP + p] = rec.x;
  }
}

// ---- counting sort of heads by clamped degree (33 bins) ----
__global__ void hist_deg(const int* __restrict__ cnt, int* __restrict__ hist) {
  __shared__ int lh[NBIN];
  if (threadIdx.x < NBIN) lh[threadIdx.x] = 0;
  __syncthreads();
  int i = blockIdx.x * blockDim.x + threadIdx.x;
  if (i < N_ENT) atomicAdd(&lh[min(cnt[i], CAP)], 1);
  __syncthreads();
  if (threadIdx.x < NBIN) atomicAdd(&hist[threadIdx.x], lh[threadIdx.x]);
}

__global__ void scan_deg(const int* __restrict__ hist, int* __restrict__ binCur) {
  if (threadIdx.x == 0) {
    int s = 0;
    for (int b = 0; b < NBIN; ++b) { binCur[b] = s; s += hist[b]; }
  }
}

// order[pos] = n | (len << 18); heads grouped by degree -> equal trip counts
// for the 4 groups of a wave. Block-aggregated scatter: LDS atomics give the
// in-block rank, one global atomicAdd per (block, bin) claims the base.
__global__ void scatter_deg(const int* __restrict__ cnt,
                            int* __restrict__ binCur,
                            unsigned* __restrict__ order) {
  __shared__ int lh[NBIN];
  __shared__ int lbase[NBIN];
  if (threadIdx.x < NBIN) lh[threadIdx.x] = 0;
  __syncthreads();
  int i = blockIdx.x * blockDim.x + threadIdx.x;
  int d = 0, rank = 0;
  bool valid = (i < N_ENT);
  if (valid) {
    d = min(cnt[i], CAP);
    rank = atomicAdd(&lh[d], 1);
  }
  __syncthreads();
  if (threadIdx.x < NBIN)
    lbase[threadIdx.x] = atomicAdd(&binCur[threadIdx.x], lh[threadIdx.x]);
  __syncthreads();
  if (valid)
    order[lbase[d] + rank] = (unsigned)i | ((unsigned)d << 18);
}

// persistent hop kernel: wave = 4 groups x 16 lanes, 4 heads/wave, heads taken
// from the degree-sorted order[] (len packed in bits 18..23 -> no cnt load).
// Gathers are bf16 rows (128 B = 1 line). Softmax un-maxed (logits << 88).
// HOP==1: heads = ent0 (f32), gather = ent0b, out = h1b (bf16)
// HOP==2: heads = h1b, gather = h1b, out = 0.25*ent0 + 0.5*eh + h2 (f32)
template <int HOP>
__global__ __launch_bounds__(256, 8) void hop_kernel(
    const float* __restrict__ ent0,
    const ushort* __restrict__ entb,     // bf16 gather table
    const float4* __restrict__ Qg,
    const unsigned* __restrict__ order,
    const unsigned* __restrict__ bucket,
    uint2* __restrict__ outb,            // HOP1
    float* __restrict__ outf) {          // HOP2
  __shared__ float4 sQ[N_REL * 32];   // [r][half(2)][sub(16)]
  for (int i = threadIdx.x; i < N_REL * 32; i += blockDim.x) sQ[i] = Qg[i];
  __syncthreads();
  const int lane = threadIdx.x & 63;
  const int sub = lane & 15;
  const int grp = lane >> 4;
  const int wave = (blockIdx.x * blockDim.x + threadIdx.x) >> 6;
  const int nWaves = (gridDim.x * blockDim.x) >> 6;
  const uint2* gtab = (const uint2*)entb;
  for (int n4 = wave * 4; n4 < N_ENT; n4 += nWaves * 4) {
    unsigned oe = order[n4 + grp];    // N_ENT % 4 == 0 -> always < N_ENT
    int n = (int)(oe & 0x3FFFFu);
    int len = (int)(oe >> 18);
    float4 eh;
    if (HOP == 1)
      eh = ((const float4*)(ent0 + (size_t)n * DIM))[sub];
    else
      eh = unpack4(gtab[(size_t)n * 16 + sub]);
    int b = n * CAP;
    float l = 0.f;
    float4 acc = make_float4(0.f, 0.f, 0.f, 0.f);
    // depth-2 software pipeline over the segment (predicated per group)
    unsigned p0 = 0u, p1 = 0u;
    uint2 t0 = make_uint2(0u, 0u), t1 = t0;
    if (0 < len) { p0 = bucket[b];     t0 = gtab[(size_t)(p0 & 0x3FFFFu) * 16 + sub]; }
    if (1 < len) { p1 = bucket[b + 1]; t1 = gtab[(size_t)(p1 & 0x3FFFFu) * 16 + sub]; }
    for (int i = 0; __any(i < len); ++i) {
      unsigned p2 = 0u;
      uint2 t2 = make_uint2(0u, 0u);
      if (i + 2 < len) { p2 = bucket[b + i + 2];
                         t2 = gtab[(size_t)(p2 & 0x3FFFFu) * 16 + sub]; }
      if (i < len) {
        int r = (int)(p0 >> 18);
        float4 qh = sQ[r * 32 + sub];
        float4 qt = sQ[r * 32 + 16 + sub];
        float4 et = unpack4(t0);
        float d = eh.x * qh.x + eh.y * qh.y + eh.z * qh.z + eh.w * qh.w
                + et.x * qt.x + et.y * qt.y + et.z * qt.z + et.w * qt.w;
        d = red16(d);
        float v = d > 0.f ? d : LEAKY * d;
        float ex = __expf(v);
        l += ex;
        acc.x = fmaf(ex, et.x, acc.x);
        acc.y = fmaf(ex, et.y, acc.y);
        acc.z = fmaf(ex, et.z, acc.z);
        acc.w = fmaf(ex, et.w, acc.w);
      }
      p0 = p1; t0 = t1; p1 = p2; t1 = t2;
    }
    float inv = (l > 0.f) ? 1.f / l : 0.f;
    float4 v;
    v.x = fmaf(acc.x, inv, eh.x);
    v.y = fmaf(acc.y, inv, eh.y);
    v.z = fmaf(acc.z, inv, eh.z);
    v.w = fmaf(acc.w, inv, eh.w);
    float s = v.x * v.x + v.y * v.y + v.z * v.z + v.w * v.w;
    s = red16(s);
    float rn = 1.f / fmaxf(sqrtf(s), 1e-12f);
    if (HOP == 1) {
      outb[(size_t)n * 16 + sub] = make_uint2(pk(v.x * rn, v.y * rn),
                                              pk(v.z * rn, v.w * rn));
    } else {
      float4 e0 = ((const float4*)(ent0 + (size_t)n * DIM))[sub];
      float4 o;
      o.x = fmaf(0.25f, e0.x, fmaf(0.5f, eh.x, v.x * rn));
      o.y = fmaf(0.25f, e0.y, fmaf(0.5f, eh.y, v.y * rn));
      o.z = fmaf(0.25f, e0.z, fmaf(0.5f, eh.z, v.z * rn));
      o.w = fmaf(0.25f, e0.w, fmaf(0.5f, eh.w, v.w * rn));
      ((float4*)(outf + (size_t)n * DIM))[sub] = o;
    }
  }
}

extern "C" void kernel_launch(void* const* d_in, const int* in_sizes, int n_in,
                              void* d_out, int out_size, void* d_ws, size_t ws_size,
                              hipStream_t stream) {
  const float* ent0 = (const float*)d_in[0];
  const float* rel  = (const float*)d_in[1];
  const float* W    = (const float*)d_in[2];
  const int* edge_index = (const int*)d_in[3];
  const int* etype      = (const int*)d_in[4];
  const int* head = edge_index;            // edge_index[0, :]
  const int* tail = edge_index + N_EDGE;   // edge_index[1, :]
  float* out = (float*)d_out;

  // workspace (~78.4 MB): Q | cursor | bucket | ent0b | h1b | order | hist |
  // binCur | qcnt  (128 B-aligned). Color queues ALIAS h1b (dead until hop1):
  // 16 x 80000 x 8 B = 10.24 MB <= 25.6 MB.
  char* ws = (char*)d_ws;
  float*    Q      = (float*)ws;                              // 16384 B
  int*      cursor = (int*)(ws + 16384);                      // 800000 B
  unsigned* bucket = (unsigned*)(ws + 816384);                // 25.6 MB
  ushort*   ent0b  = (ushort*)(ws + 816384 + 25600000);       // 25.6 MB
  ushort*   h1b    = (ushort*)(ws + 816384 + 51200000);       // 25.6 MB
  unsigned* order  = (unsigned*)(ws + 816384 + 76800000);     // 800000 B
  int*      hist   = (int*)(ws + 816384 + 77600000);          // 132 B (pad 128)
  int*      binCur = (int*)(ws + 816384 + 77600128);          // 132 B (pad 128)
  int*      qcnt   = (int*)(ws + 816384 + 77600256);          // 64 B
  uint2*    qdata  = (uint2*)h1b;                             // aliased

  // ---- preamble: prep (Q + bf16 table + zero counters) ----
  prep<<<(N_ENT * DIM / 4 + 255) / 256, 256, 0, stream>>>(
      W, rel, Q, (const float4*)ent0, (uint2*)ent0b, cursor, hist, qcnt);

  // ---- two-phase bucket build: route (1 pass) + fill2 (band-local) ----
  route<<<(N_EDGE / 4 + 255) / 256, 256, 0, stream>>>(
      (const int4*)head, (const int4*)tail, (const int4*)etype, qcnt, qdata);
  fill2<<<NCOLOR * BPC, 256, 0, stream>>>(qcnt, qdata, cursor, bucket);

  // ---- degree-grouped schedule: counting sort of heads (33 bins) ----
  hist_deg<<<(N_ENT + 255) / 256, 256, 0, stream>>>(cursor, hist);
  scan_deg<<<1, 64, 0, stream>>>(hist, binCur);
  scatter_deg<<<(N_ENT + 255) / 256, 256, 0, stream>>>(cursor, binCur, order);

  // ---- hops: one persistent kernel each ----
  hop_kernel<1><<<2048, 256, 0, stream>>>(ent0, ent0b, (const float4*)Q,
                                          order, bucket, (uint2*)h1b, nullptr);
  hop_kernel<2><<<2048, 256, 0, stream>>>(ent0, h1b, (const float4*)Q,
                                          order, bucket, nullptr, out);
}

// Round 6
// 283.122 us; speedup vs baseline: 1.2884x; 1.2419x over previous
//
#include <hip/hip_runtime.h>
#include <hip/hip_bf16.h>

// KGAT-style 2-hop relational graph attention on MI355X — round 13.
//
// vs round 12 (FAILED, absmax 0.79): SQCAP was 3000 = the MEAN sub-queue
// load (500 heads x deg 6), sigma ~55 -> ~half the sub-queues overflowed and
// subroute dropped ~1% of edges. Fix: SQCAP 3500 (mean + 9.1 sigma, same
// discipline as QCAP 80000 vs mean 75000). Aliased footprint 21.44 MB
// (qdata 10.24 + sqdata 11.2) still < h1b's 25.6 MB. Nothing else changed.
//
// Design under test (from round 12, vs round 11's 351.6 us / fill2 104 us):
//  - Atomic-free LDS-staged bucket build. subroute: color queue -> 25
//    sub-queues per color (sub-band = 500 heads), block-aggregated, coalesced
//    chunks. fill3: one block per sub-band bins ~3000 records into a 64 KB
//    LDS bucket via LDS atomics, then writes bucket region + cursor as
//    full-line coalesced uint4 stores. Zero global atomics; each bucket line
//    owned by exactly one block/XCD (kills the 13x write amplification).
//  - fill3 writes every cursor value -> prep's cursor zeroing deleted.
//  - route / degree-grouped hop schedule / bf16 tables unchanged.
//
// dtypes: all float32 (reference), indices int32 (harness int64->int32).

#define N_ENT  200000
#define N_EDGE 1200000
#define N_REL  32
#define DIM    64
#define LEAKY  0.2f
#define CAP    32                                      // bucket slots per head
#define NCOLOR 16
#define BAND (N_ENT / NCOLOR)                          // 12500 heads per color
#define NBIN   (CAP + 1)                               // degree bins 0..32
#define QCAP   80000                                   // records per color queue
#define NSUBC  25                                      // sub-bands per color
#define SUBH   (BAND / NSUBC)                          // 500 heads per sub-band
#define NSUB   (NCOLOR * NSUBC)                        // 400 sub-bands total
#define SQCAP  3500                                    // mean 3000 + 9.1 sigma
#define NSRB   ((QCAP + 1023) / 1024)                  // 79 subroute blocks/color

template <int CTRL>
__device__ __forceinline__ float dpp_add(float x) {
  int t = __builtin_amdgcn_update_dpp(0, __float_as_int(x), CTRL, 0xF, 0xF, true);
  return x + __int_as_float(t);
}
// 16-lane (DPP row) allreduce sum; result valid in all 16 lanes of the row.
__device__ __forceinline__ float red16(float x) {
  x = dpp_add<0xB1>(x);    // quad_perm [1,0,3,2]  (xor 1)
  x = dpp_add<0x4E>(x);    // quad_perm [2,3,0,1]  (xor 2)
  x = dpp_add<0x124>(x);   // row_ror:4
  x = dpp_add<0x128>(x);   // row_ror:8
  return x;
}

// 4 bf16 (as 2 uints, low/high packed) -> float4
__device__ __forceinline__ float4 unpack4(uint2 u) {
  float4 t;
  t.x = __uint_as_float(u.x << 16);
  t.y = __uint_as_float(u.x & 0xFFFF0000u);
  t.z = __uint_as_float(u.y << 16);
  t.w = __uint_as_float(u.y & 0xFFFF0000u);
  return t;
}
// two f32 -> packed bf16 pair (round-to-nearest-even)
__device__ __forceinline__ unsigned pk(float a, float b) {
  unsigned ua = __float_as_uint(a);
  ua += 0x7FFFu + ((ua >> 16) & 1u);
  unsigned ub = __float_as_uint(b);
  ub += 0x7FFFu + ((ub >> 16) & 1u);
  return (ua >> 16) | (ub & 0xFFFF0000u);
}

// prep: build Q (Q[r*128+k] = W[k,:] . R[r,:]) + convert ent0 -> bf16 table
//       + zero degree hist / color-queue counts / sub-queue counts
//       (cursor is fully written by fill3 -> no zeroing needed)
__global__ void prep(const float* __restrict__ W, const float* __restrict__ R,
                     float* __restrict__ Q,
                     const float4* __restrict__ ent04,
                     uint2* __restrict__ ent0b,
                     int* __restrict__ hist,
                     int* __restrict__ qcnt,
                     int* __restrict__ sqcnt) {
  int i = blockIdx.x * blockDim.x + threadIdx.x;
  if (i < N_REL * 2 * DIM) {
    int r = i >> 7;
    int k = i & 127;
    float acc = 0.f;
#pragma unroll 8
    for (int j = 0; j < DIM; ++j)
      acc += W[k * DIM + j] * R[r * DIM + j];
    Q[i] = acc;
  }
  if (i < NBIN) hist[i] = 0;
  if (i < NCOLOR) qcnt[i] = 0;
  if (i < NSUB) sqcnt[i] = 0;
  if (i < N_ENT * DIM / 4) {
    float4 v = ent04[i];
    ent0b[i] = make_uint2(pk(v.x, v.y), pk(v.z, v.w));
  }
}

// route: single pass over edges; partition into 16 per-color queues.
// Record = (tail | type<<18, head). Block-aggregated: LDS rank + one global
// atomicAdd per (block, color) -> per-color ~512 B contiguous chunks.
__global__ void route(const int4* __restrict__ head4,
                      const int4* __restrict__ tail4,
                      const int4* __restrict__ type4,
                      int* __restrict__ qcnt,
                      uint2* __restrict__ qdata) {
  __shared__ int lcnt[NCOLOR];
  __shared__ int lbase[NCOLOR];
  if (threadIdx.x < NCOLOR) lcnt[threadIdx.x] = 0;
  __syncthreads();
  int i = blockIdx.x * blockDim.x + threadIdx.x;
  bool valid = (i < N_EDGE / 4);
  int4 h = make_int4(0, 0, 0, 0), t = h, r = h;
  int c0 = 0, c1 = 0, c2 = 0, c3 = 0;
  int k0 = 0, k1 = 0, k2 = 0, k3 = 0;
  if (valid) {
    h = head4[i];
    t = tail4[i];
    r = type4[i];
    c0 = h.x / BAND; c1 = h.y / BAND; c2 = h.z / BAND; c3 = h.w / BAND;
    k0 = atomicAdd(&lcnt[c0], 1);
    k1 = atomicAdd(&lcnt[c1], 1);
    k2 = atomicAdd(&lcnt[c2], 1);
    k3 = atomicAdd(&lcnt[c3], 1);
  }
  __syncthreads();
  if (threadIdx.x < NCOLOR)
    lbase[threadIdx.x] = atomicAdd(&qcnt[threadIdx.x], lcnt[threadIdx.x]);
  __syncthreads();
  if (valid) {
    int p;
    p = lbase[c0] + k0;
    if (p < QCAP) qdata[c0 * QCAP + p] = make_uint2((unsigned)t.x | ((unsigned)r.x << 18), (unsigned)h.x);
    p = lbase[c1] + k1;
    if (p < QCAP) qdata[c1 * QCAP + p] = make_uint2((unsigned)t.y | ((unsigned)r.y << 18), (unsigned)h.y);
    p = lbase[c2] + k2;
    if (p < QCAP) qdata[c2 * QCAP + p] = make_uint2((unsigned)t.z | ((unsigned)r.z << 18), (unsigned)h.z);
    p = lbase[c3] + k3;
    if (p < QCAP) qdata[c3 * QCAP + p] = make_uint2((unsigned)t.w | ((unsigned)r.w << 18), (unsigned)h.w);
  }
}

// subroute: split each color queue into 25 sub-band queues (block-aggregated,
// ~41-record coalesced chunks; ~79 contenders per sqcnt address).
__global__ void subroute(const int* __restrict__ qcnt,
                         const uint2* __restrict__ qdata,
                         int* __restrict__ sqcnt,
                         uint2* __restrict__ sqdata) {
  __shared__ int lcnt[NSUBC];
  __shared__ int lbase[NSUBC];
  if (threadIdx.x < NSUBC) lcnt[threadIdx.x] = 0;
  __syncthreads();
  int c = blockIdx.x / NSRB;
  int slice = blockIdx.x - c * NSRB;
  int n = min(qcnt[c], QCAP);
  int base = slice * 1024;
  if (base >= n) return;
  int lim = min(n, base + 1024);
  const uint2* q = qdata + (size_t)c * QCAP;
  int hbase = c * BAND;
  uint2 rec[4];
  int s[4], rk[4], cnt = 0;
#pragma unroll
  for (int j = 0; j < 4; ++j) {
    int k = base + j * 256 + threadIdx.x;
    if (k < lim) {
      rec[cnt] = q[k];
      s[cnt] = (int)(rec[cnt].y - (unsigned)hbase) / SUBH;   // 0..24
      rk[cnt] = atomicAdd(&lcnt[s[cnt]], 1);
      ++cnt;
    }
  }
  __syncthreads();
  if (threadIdx.x < NSUBC)
    lbase[threadIdx.x] = atomicAdd(&sqcnt[c * NSUBC + threadIdx.x], lcnt[threadIdx.x]);
  __syncthreads();
  for (int j = 0; j < cnt; ++j) {
    int p = lbase[s[j]] + rk[j];
    if (p < SQCAP)
      sqdata[(size_t)(c * NSUBC + s[j]) * SQCAP + p] = rec[j];
  }
}

// fill3: one block per sub-band. Bin ~3000 records into a 64 KB LDS bucket
// with LDS atomics, then write bucket region + cursor fully coalesced.
// No global atomics; each bucket line written once, by one block.
__global__ void fill3(const int* __restrict__ sqcnt,
                      const uint2* __restrict__ sqdata,
                      int* __restrict__ cursor,
                      unsigned* __restrict__ bucket) {
  __shared__ unsigned lbucket[SUBH * CAP];   // 64000 B
  __shared__ int lcur[SUBH];                 // 2000 B
  int g = blockIdx.x;                        // global sub-band id
  int hbase = (g / NSUBC) * BAND + (g - (g / NSUBC) * NSUBC) * SUBH;
  for (int i = threadIdx.x; i < SUBH; i += blockDim.x) lcur[i] = 0;
  __syncthreads();
  int n = min(sqcnt[g], SQCAP);
  const uint2* q = sqdata + (size_t)g * SQCAP;
  for (int k = threadIdx.x; k < n; k += blockDim.x) {
    uint2 rec = q[k];
    int lh = (int)rec.y - hbase;             // 0..SUBH-1
    int p = atomicAdd(&lcur[lh], 1);
    if (p < CAP) lbucket[lh * CAP + p] = rec.x;
  }
  __syncthreads();
  // coalesced writeout (slots beyond lcur[lh] are garbage but never read)
  const uint4* lb4 = (const uint4*)lbucket;
  uint4* gb4 = (uint4*)(bucket + (size_t)hbase * CAP);
  for (int i = threadIdx.x; i < SUBH * CAP / 4; i += blockDim.x) gb4[i] = lb4[i];
  for (int i = threadIdx.x; i < SUBH; i += blockDim.x) cursor[hbase + i] = lcur[i];
}

// ---- counting sort of heads by clamped degree (33 bins) ----
__global__ void hist_deg(const int* __restrict__ cnt, int* __restrict__ hist) {
  __shared__ int lh[NBIN];
  if (threadIdx.x < NBIN) lh[threadIdx.x] = 0;
  __syncthreads();
  int i = blockIdx.x * blockDim.x + threadIdx.x;
  if (i < N_ENT) atomicAdd(&lh[min(cnt[i], CAP)], 1);
  __syncthreads();
  if (threadIdx.x < NBIN) atomicAdd(&hist[threadIdx.x], lh[threadIdx.x]);
}

__global__ void scan_deg(const int* __restrict__ hist, int* __restrict__ binCur) {
  if (threadIdx.x == 0) {
    int s = 0;
    for (int b = 0; b < NBIN; ++b) { binCur[b] = s; s += hist[b]; }
  }
}

// order[pos] = n | (len << 18); heads grouped by degree -> equal trip counts
// for the 4 groups of a wave. Block-aggregated scatter: LDS atomics give the
// in-block rank, one global atomicAdd per (block, bin) claims the base.
__global__ void scatter_deg(const int* __restrict__ cnt,
                            int* __restrict__ binCur,
                            unsigned* __restrict__ order) {
  __shared__ int lh[NBIN];
  __shared__ int lbase[NBIN];
  if (threadIdx.x < NBIN) lh[threadIdx.x] = 0;
  __syncthreads();
  int i = blockIdx.x * blockDim.x + threadIdx.x;
  int d = 0, rank = 0;
  bool valid = (i < N_ENT);
  if (valid) {
    d = min(cnt[i], CAP);
    rank = atomicAdd(&lh[d], 1);
  }
  __syncthreads();
  if (threadIdx.x < NBIN)
    lbase[threadIdx.x] = atomicAdd(&binCur[threadIdx.x], lh[threadIdx.x]);
  __syncthreads();
  if (valid)
    order[lbase[d] + rank] = (unsigned)i | ((unsigned)d << 18);
}

// persistent hop kernel: wave = 4 groups x 16 lanes, 4 heads/wave, heads taken
// from the degree-sorted order[] (len packed in bits 18..23 -> no cnt load).
// Gathers are bf16 rows (128 B = 1 line). Softmax un-maxed (logits << 88).
// HOP==1: heads = ent0 (f32), gather = ent0b, out = h1b (bf16)
// HOP==2: heads = h1b, gather = h1b, out = 0.25*ent0 + 0.5*eh + h2 (f32)
template <int HOP>
__global__ __launch_bounds__(256, 8) void hop_kernel(
    const float* __restrict__ ent0,
    const ushort* __restrict__ entb,     // bf16 gather table
    const float4* __restrict__ Qg,
    const unsigned* __restrict__ order,
    const unsigned* __restrict__ bucket,
    uint2* __restrict__ outb,            // HOP1
    float* __restrict__ outf) {          // HOP2
  __shared__ float4 sQ[N_REL * 32];   // [r][half(2)][sub(16)]
  for (int i = threadIdx.x; i < N_REL * 32; i += blockDim.x) sQ[i] = Qg[i];
  __syncthreads();
  const int lane = threadIdx.x & 63;
  const int sub = lane & 15;
  const int grp = lane >> 4;
  const int wave = (blockIdx.x * blockDim.x + threadIdx.x) >> 6;
  const int nWaves = (gridDim.x * blockDim.x) >> 6;
  const uint2* gtab = (const uint2*)entb;
  for (int n4 = wave * 4; n4 < N_ENT; n4 += nWaves * 4) {
    unsigned oe = order[n4 + grp];    // N_ENT % 4 == 0 -> always < N_ENT
    int n = (int)(oe & 0x3FFFFu);
    int len = (int)(oe >> 18);
    float4 eh;
    if (HOP == 1)
      eh = ((const float4*)(ent0 + (size_t)n * DIM))[sub];
    else
      eh = unpack4(gtab[(size_t)n * 16 + sub]);
    int b = n * CAP;
    float l = 0.f;
    float4 acc = make_float4(0.f, 0.f, 0.f, 0.f);
    // depth-2 software pipeline over the segment (predicated per group)
    unsigned p0 = 0u, p1 = 0u;
    uint2 t0 = make_uint2(0u, 0u), t1 = t0;
    if (0 < len) { p0 = bucket[b];     t0 = gtab[(size_t)(p0 & 0x3FFFFu) * 16 + sub]; }
    if (1 < len) { p1 = bucket[b + 1]; t1 = gtab[(size_t)(p1 & 0x3FFFFu) * 16 + sub]; }
    for (int i = 0; __any(i < len); ++i) {
      unsigned p2 = 0u;
      uint2 t2 = make_uint2(0u, 0u);
      if (i + 2 < len) { p2 = bucket[b + i + 2];
                         t2 = gtab[(size_t)(p2 & 0x3FFFFu) * 16 + sub]; }
      if (i < len) {
        int r = (int)(p0 >> 18);
        float4 qh = sQ[r * 32 + sub];
        float4 qt = sQ[r * 32 + 16 + sub];
        float4 et = unpack4(t0);
        float d = eh.x * qh.x + eh.y * qh.y + eh.z * qh.z + eh.w * qh.w
                + et.x * qt.x + et.y * qt.y + et.z * qt.z + et.w * qt.w;
        d = red16(d);
        float v = d > 0.f ? d : LEAKY * d;
        float ex = __expf(v);
        l += ex;
        acc.x = fmaf(ex, et.x, acc.x);
        acc.y = fmaf(ex, et.y, acc.y);
        acc.z = fmaf(ex, et.z, acc.z);
        acc.w = fmaf(ex, et.w, acc.w);
      }
      p0 = p1; t0 = t1; p1 = p2; t1 = t2;
    }
    float inv = (l > 0.f) ? 1.f / l : 0.f;
    float4 v;
    v.x = fmaf(acc.x, inv, eh.x);
    v.y = fmaf(acc.y, inv, eh.y);
    v.z = fmaf(acc.z, inv, eh.z);
    v.w = fmaf(acc.w, inv, eh.w);
    float s = v.x * v.x + v.y * v.y + v.z * v.z + v.w * v.w;
    s = red16(s);
    float rn = 1.f / fmaxf(sqrtf(s), 1e-12f);
    if (HOP == 1) {
      outb[(size_t)n * 16 + sub] = make_uint2(pk(v.x * rn, v.y * rn),
                                              pk(v.z * rn, v.w * rn));
    } else {
      float4 e0 = ((const float4*)(ent0 + (size_t)n * DIM))[sub];
      float4 o;
      o.x = fmaf(0.25f, e0.x, fmaf(0.5f, eh.x, v.x * rn));
      o.y = fmaf(0.25f, e0.y, fmaf(0.5f, eh.y, v.y * rn));
      o.z = fmaf(0.25f, e0.z, fmaf(0.5f, eh.z, v.z * rn));
      o.w = fmaf(0.25f, e0.w, fmaf(0.5f, eh.w, v.w * rn));
      ((float4*)(outf + (size_t)n * DIM))[sub] = o;
    }
  }
}

extern "C" void kernel_launch(void* const* d_in, const int* in_sizes, int n_in,
                              void* d_out, int out_size, void* d_ws, size_t ws_size,
                              hipStream_t stream) {
  const float* ent0 = (const float*)d_in[0];
  const float* rel  = (const float*)d_in[1];
  const float* W    = (const float*)d_in[2];
  const int* edge_index = (const int*)d_in[3];
  const int* etype      = (const int*)d_in[4];
  const int* head = edge_index;            // edge_index[0, :]
  const int* tail = edge_index + N_EDGE;   // edge_index[1, :]
  float* out = (float*)d_out;

  // workspace (~78.4 MB): Q | cursor | bucket | ent0b | h1b | order | hist |
  // binCur | qcnt | sqcnt  (128 B-aligned). qdata (10.24 MB) and sqdata
  // (11.2 MB) both ALIAS h1b (dead until hop1): 21.44 MB <= 25.6 MB.
  char* ws = (char*)d_ws;
  float*    Q      = (float*)ws;                              // 16384 B
  int*      cursor = (int*)(ws + 16384);                      // 800000 B
  unsigned* bucket = (unsigned*)(ws + 816384);                // 25.6 MB
  ushort*   ent0b  = (ushort*)(ws + 816384 + 25600000);       // 25.6 MB
  ushort*   h1b    = (ushort*)(ws + 816384 + 51200000);       // 25.6 MB
  unsigned* order  = (unsigned*)(ws + 816384 + 76800000);     // 800000 B
  int*      hist   = (int*)(ws + 816384 + 77600000);          // 132 B (pad 128)
  int*      binCur = (int*)(ws + 816384 + 77600128);          // 132 B (pad 128)
  int*      qcnt   = (int*)(ws + 816384 + 77600256);          // 64 B (pad 128)
  int*      sqcnt  = (int*)(ws + 816384 + 77600384);          // 1600 B
  uint2*    qdata  = (uint2*)h1b;                             // aliased
  uint2*    sqdata = (uint2*)(h1b + 10240000 / 2);            // aliased (+10.24 MB)

  // ---- preamble: prep (Q + bf16 table + zero counters) ----
  prep<<<(N_ENT * DIM / 4 + 255) / 256, 256, 0, stream>>>(
      W, rel, Q, (const float4*)ent0, (uint2*)ent0b, hist, qcnt, sqcnt);

  // ---- atomic-free bucket build: route -> subroute -> fill3 ----
  route<<<(N_EDGE / 4 + 255) / 256, 256, 0, stream>>>(
      (const int4*)head, (const int4*)tail, (const int4*)etype, qcnt, qdata);
  subroute<<<NCOLOR * NSRB, 256, 0, stream>>>(qcnt, qdata, sqcnt, sqdata);
  fill3<<<NSUB, 256, 0, stream>>>(sqcnt, sqdata, cursor, bucket);

  // ---- degree-grouped schedule: counting sort of heads (33 bins) ----
  hist_deg<<<(N_ENT + 255) / 256, 256, 0, stream>>>(cursor, hist);
  scan_deg<<<1, 64, 0, stream>>>(hist, binCur);
  scatter_deg<<<(N_ENT + 255) / 256, 256, 0, stream>>>(cursor, binCur, order);

  // ---- hops: one persistent kernel each ----
  hop_kernel<1><<<2048, 256, 0, stream>>>(ent0, ent0b, (const float4*)Q,
                                          order, bucket, (uint2*)h1b, nullptr);
  hop_kernel<2><<<2048, 256, 0, stream>>>(ent0, h1b, (const float4*)Q,
                                          order, bucket, nullptr, out);
}